// Round 5
// baseline (399.153 us; speedup 1.0000x reference)
//
#include <hip/hip_runtime.h>
#include <hip/hip_fp16.h>

#define B_  32
#define L_  2048
#define H_  512
#define T_  2047      // L_-1 keys enter the scan
#define CA  32        // chunk size
#define NC  64        // chunks per batch (64*32 = 2048 >= 2047, last row padded)
#define EPSF 1e-6f

// ---- wave64 sum reduction via DPP; full sum lands in lane 63 ----
template <int CTRL>
__device__ __forceinline__ float dpp_shift_add(float x) {
  int t = __builtin_amdgcn_update_dpp(0, __float_as_int(x), CTRL, 0xf, 0xf, true);
  return x + __int_as_float(t);
}
__device__ __forceinline__ float wave_reduce_lane63(float x) {
  x = dpp_shift_add<0x111>(x);  // row_shr:1
  x = dpp_shift_add<0x112>(x);  // row_shr:2
  x = dpp_shift_add<0x114>(x);  // row_shr:4
  x = dpp_shift_add<0x118>(x);  // row_shr:8
  x = dpp_shift_add<0x142>(x);  // row_bcast:15
  x = dpp_shift_add<0x143>(x);  // row_bcast:31
  return x;                     // valid in lane 63
}

// async global->LDS, 16B per lane; LDS base must be wave-uniform
__device__ __forceinline__ void load_lds16(const float* g, float* l) {
  __builtin_amdgcn_global_load_lds(
      (const __attribute__((address_space(1))) unsigned int*)(g),
      (__attribute__((address_space(3))) unsigned int*)(l), 16, 0, 0);
}
__device__ __forceinline__ void load_lds16h(const unsigned short* g, unsigned short* l) {
  __builtin_amdgcn_global_load_lds(
      (const __attribute__((address_space(1))) unsigned int*)(g),
      (__attribute__((address_space(3))) unsigned int*)(l), 16, 0, 0);
}

// =====================================================================
// Kernel A: per (batch, chunk): round keys to fp16 (writes Kh copy when
// Kh != nullptr), then Gram G = K~ K~^T, dvec = diag(G)+eps, and
// X = (I + D^{-1} triu(G,1))^{-1} D^{-1}.
// Lane j holds column j of X; stored contiguously: flat[j*32+s] = X[s][j].
// grid (NC, B_), 256 threads (4 waves). Wave w register-holds rows 8w..8w+7.
// =====================================================================
__global__ __launch_bounds__(256) void
deltarule_gram(const float* __restrict__ hidden,
               float* __restrict__ tmT, float* __restrict__ dvec,
               unsigned short* __restrict__ Kh) {
  const int cb = blockIdx.x, b = blockIdx.y;
  const int tid = threadIdx.x, lane = tid & 63, wv = tid >> 6;
  __shared__ __align__(16) float Kc[CA * H_];   // 64 KB
  __shared__ float G[CA * 33];                  // +1 pad

  const float* kb = hidden + ((size_t)b * L_ + (size_t)cb * CA) * H_;
#pragma unroll
  for (int u = 0; u < 16; ++u) {                // 16 issues x 4 waves = 64 segs
    const int off = (u * 4 + wv) * 256;
    load_lds16(kb + off + 4 * lane, &Kc[off]);
  }
  __asm__ volatile("s_waitcnt vmcnt(0)" ::: "memory");
  __syncthreads();
  if (cb == NC - 1) {                           // zero padded key row 31
    if (tid < 128) *(float4*)&Kc[31 * H_ + 4 * tid] = make_float4(0.f, 0.f, 0.f, 0.f);
    __syncthreads();
  }

  // round to fp16 (in place) + write fp16 copy
  if (Kh) {
    unsigned int* dst = (unsigned int*)(Kh + ((size_t)b * L_ + (size_t)cb * CA) * H_);
#pragma unroll
    for (int u = 0; u < 32; ++u) {
      const int i = u * 256 + tid;              // pair index < 8192
      float2 v = *(const float2*)&Kc[2 * i];
      __half2 h2 = __floats2half2_rn(v.x, v.y);
      dst[i] = *(const unsigned int*)&h2;
      *(float2*)&Kc[2 * i] = __half22float2(h2);
    }
    __syncthreads();
  }

  // register rows: lane covers h in [4*lane,4*lane+4) u [256+4*lane, ...)
  float kr[8][8];
#pragma unroll
  for (int i = 0; i < 8; ++i) {
    const int r = 8 * wv + i;
    *(float4*)&kr[i][0] = *(const float4*)&Kc[r * H_ + 4 * lane];
    *(float4*)&kr[i][4] = *(const float4*)&Kc[r * H_ + 256 + 4 * lane];
  }
  float g[8] = {0.f, 0.f, 0.f, 0.f, 0.f, 0.f, 0.f, 0.f};  // lane j: G[row_i][j]
  for (int j = 8 * wv; j < CA; ++j) {           // only j >= first own row (symmetry)
    float kj[8];
    *(float4*)&kj[0] = *(const float4*)&Kc[j * H_ + 4 * lane];
    *(float4*)&kj[4] = *(const float4*)&Kc[j * H_ + 256 + 4 * lane];
#pragma unroll
    for (int i = 0; i < 8; ++i) {
      float p = kr[i][0] * kj[0];
#pragma unroll
      for (int u = 1; u < 8; ++u) p = fmaf(kr[i][u], kj[u], p);
      p = wave_reduce_lane63(p);
      float s = __int_as_float(__builtin_amdgcn_readlane(__float_as_int(p), 63));
      g[i] = (lane == j) ? s : g[i];
    }
  }
  if (lane < CA) {
#pragma unroll
    for (int i = 0; i < 8; ++i) G[(8 * wv + i) * 33 + lane] = g[i];
  }
  __syncthreads();

  // back-substitution on wave 0: lane j = column j of X
  if (wv == 0) {
    const int j = lane & 31;
    float X[CA];
#pragma unroll
    for (int t = CA - 1; t >= 0; --t) {
      float inner = 0.f;
#pragma unroll
      for (int s = t + 1; s < CA; ++s) inner = fmaf(G[t * 33 + s], X[s], inner);
      X[t] = (((j == t) ? 1.f : 0.f) - inner) / (G[t * 33 + t] + EPSF);
    }
    if (lane < CA) {
      const size_t base = ((size_t)b * NC + cb) * (CA * CA);
#pragma unroll
      for (int u = 0; u < 8; ++u)
        *(float4*)&tmT[base + j * CA + 4 * u] =
            make_float4(X[4 * u], X[4 * u + 1], X[4 * u + 2], X[4 * u + 3]);
      dvec[((size_t)b * NC + cb) * CA + lane] = G[j * 33 + j] + EPSF;
    }
  }
}

// =====================================================================
// Kernel B (fp16 path): backward chunked scan + fused output GEMM.
// grid (B_), 512 threads (8 waves). Depth-2 async prefetch of fp16 key
// chunks into a 3-buffer LDS rotation; raw s_barrier + targeted
// s_waitcnt vmcnt(4) keeps the prefetch in flight across barriers.
// sigma computed redundantly in every wave (2 barriers per pass).
// =====================================================================
__global__ __launch_bounds__(512) void
deltarule_scan_f16(const float* __restrict__ hidden,
                   const unsigned short* __restrict__ Kh,
                   const float* __restrict__ Wm, const float* __restrict__ bias,
                   const float* __restrict__ tmT, const float* __restrict__ dvec,
                   float* __restrict__ out) {
  const int b = blockIdx.x, tid = threadIdx.x, lane = tid & 63, wv = tid >> 6;
  __shared__ __align__(16) unsigned short Kc[3][CA * H_];  // 96 KB
  __shared__ float Tm[2][CA * 33];
  __shared__ float Yv[CA];
  __shared__ float2 SigS[CA];
  __shared__ __align__(16) float Wv[H_];
  __shared__ __align__(16) float Ctx[H_];

  const float* hb = hidden + (size_t)b * L_ * H_;
  const unsigned short* kbb = Kh + (size_t)b * L_ * H_;

  float wh = hb[(size_t)(L_ - 1) * H_ + tid];   // running w (query state), fp32
  Wv[tid] = wh;
  float ch = 0.f;

  // ---- preloop: [K(63) lds x4][Tm63,D63 regs][K(62) lds x4][stage Tm63] ----
  {
    const unsigned short* kp = kbb + (size_t)(NC - 1) * CA * H_;
#pragma unroll
    for (int u = 0; u < 4; ++u) {
      const int off = (u * 8 + wv) * 512;       // 512 halves per wave-issue
      load_lds16h(kp + off + 8 * lane, &Kc[(NC - 1) % 3][off]);
    }
  }
  asm volatile("" ::: "memory");
  const size_t tbP = (size_t)b * NC + (NC - 1);
  float2 tmR = *(const float2*)&tmT[tbP * (CA * CA) + 2 * tid];
  float dR = dvec[tbP * CA + (lane & 31)];
  asm volatile("" ::: "memory");
  {
    const unsigned short* kp = kbb + (size_t)(NC - 2) * CA * H_;
#pragma unroll
    for (int u = 0; u < 4; ++u) {
      const int off = (u * 8 + wv) * 512;
      load_lds16h(kp + off + 8 * lane, &Kc[(NC - 2) % 3][off]);
    }
  }
  asm volatile("" ::: "memory");
  {
    const int f0 = 2 * tid;
    Tm[1][(f0 >> 5) * 33 + (f0 & 31)] = tmR.x;        // compiler waits tmR's load,
    Tm[1][((f0 + 1) >> 5) * 33 + ((f0 + 1) & 31)] = tmR.y;  // leaves K(62) in flight
  }
  float dCur = dR;
  asm volatile("s_waitcnt vmcnt(4) lgkmcnt(0)\n\ts_barrier" ::: "memory");

  for (int c = NC - 1; c >= 0; --c) {
    const int rb = c % 3;

    // ---- future loads: Tm/D(c-1) to regs, K(c-2) async to LDS ----
    if (c >= 1) {
      const size_t tb = (size_t)b * NC + (c - 1);
      tmR = *(const float2*)&tmT[tb * (CA * CA) + 2 * tid];
      dR = dvec[tb * CA + (lane & 31)];
    }
    asm volatile("" ::: "memory");
    if (c >= 2) {
      const unsigned short* kp = kbb + (size_t)(c - 2) * CA * H_;
#pragma unroll
      for (int u = 0; u < 4; ++u) {
        const int off = (u * 8 + wv) * 512;
        load_lds16h(kp + off + 8 * lane, &Kc[(c - 2) % 3][off]);
      }
    }
    asm volatile("" ::: "memory");

    // ---- dot phase: wave wv computes y for rows 4wv..4wv+3 ----
    {
      float4 wa = *(const float4*)&Wv[8 * lane];
      float4 wb2 = *(const float4*)&Wv[8 * lane + 4];
#pragma unroll
      for (int i = 0; i < 4; ++i) {
        const int r = 4 * wv + i;
        uint4 kw = *(const uint4*)&Kc[rb][r * H_ + 8 * lane];
        float2 f0 = __half22float2(*(__half2*)&kw.x);
        float2 f1 = __half22float2(*(__half2*)&kw.y);
        float2 f2 = __half22float2(*(__half2*)&kw.z);
        float2 f3 = __half22float2(*(__half2*)&kw.w);
        float p = f0.x * wa.x;
        p = fmaf(f0.y, wa.y, p); p = fmaf(f1.x, wa.z, p); p = fmaf(f1.y, wa.w, p);
        p = fmaf(f2.x, wb2.x, p); p = fmaf(f2.y, wb2.y, p);
        p = fmaf(f3.x, wb2.z, p); p = fmaf(f3.y, wb2.w, p);
        p = wave_reduce_lane63(p);
        if (lane == 63) Yv[r] = p;
      }
    }
    asm volatile("s_waitcnt lgkmcnt(0)\n\ts_barrier" ::: "memory");  // b1: Yv

    // ---- sigma = X y, s = D sigma : redundant in EVERY wave ----
    {
      const int j = lane & 31, hf = lane >> 5;
      float sig = 0.f;
#pragma unroll
      for (int s0 = 0; s0 < 16; ++s0) {
        const int s = hf * 16 + s0;
        sig = fmaf(Tm[c & 1][s * 33 + j], Yv[s], sig);
      }
      sig += __shfl_xor(sig, 32);
      float sj = dCur * sig;
      if (lane < 32) SigS[j] = make_float2(sig, sj);  // identical-value race: benign
    }
    // stage Tm(c-1); compiler's reg-dep wait leaves K(c-2) in flight
    if (c >= 1) {
      const int f0 = 2 * tid;
      Tm[(c - 1) & 1][(f0 >> 5) * 33 + (f0 & 31)] = tmR.x;
      Tm[(c - 1) & 1][((f0 + 1) >> 5) * 33 + ((f0 + 1) & 31)] = tmR.y;
      dCur = dR;
    }

    // ---- update: w -= K^T sigma ; ctx += K^T s  (h = tid) ----
#pragma unroll
    for (int t = 0; t < CA; ++t) {
      float2 ss = SigS[t];                               // own-wave write, broadcast read
      float kvv = __half2float(*(const __half*)&Kc[rb][t * H_ + tid]);
      wh = fmaf(-ss.x, kvv, wh);
      ch = fmaf(ss.y, kvv, ch);
    }
    Wv[tid] = wh;

    // b_end: execution sync + Wv/Tm visible + K(c-1) complete (vmcnt(4)
    // leaves only the K(c-2) group outstanding)
    if (c >= 2) {
      asm volatile("s_waitcnt vmcnt(4) lgkmcnt(0)\n\ts_barrier" ::: "memory");
    } else {
      asm volatile("s_waitcnt vmcnt(0) lgkmcnt(0)\n\ts_barrier" ::: "memory");
    }
  }

  // ---- epilogue: out[b] = W @ ctx + bias ----
  Ctx[tid] = ch;
  __syncthreads();
  float acc = bias[tid];
  const float* wr = Wm + (size_t)tid * H_;
#pragma unroll 8
  for (int i = 0; i < H_; i += 4) {
    float4 w4 = *(const float4*)(wr + i);
    float4 cv = *(const float4*)&Ctx[i];
    acc = fmaf(w4.x, cv.x, acc); acc = fmaf(w4.y, cv.y, acc);
    acc = fmaf(w4.z, cv.z, acc); acc = fmaf(w4.w, cv.w, acc);
  }
  out[(size_t)b * H_ + tid] = acc;
}

// =====================================================================
// Kernel B fallback (fp32, round-4 structure) — used if ws too small.
// =====================================================================
__global__ __launch_bounds__(512) void
deltarule_scan_f32(const float* __restrict__ hidden,
                   const float* __restrict__ Wm, const float* __restrict__ bias,
                   const float* __restrict__ tmT, const float* __restrict__ dvec,
                   float* __restrict__ out) {
  const int b = blockIdx.x, tid = threadIdx.x, lane = tid & 63, wv = tid >> 6;
  __shared__ __align__(16) float Kc[2][CA * H_];
  __shared__ float Tm[CA * 33];
  __shared__ float Dv[CA];
  __shared__ float Yv[CA];
  __shared__ float2 SigS[CA];
  __shared__ __align__(16) float Wv[H_];
  __shared__ __align__(16) float Ctx[H_];

  const float* hb = hidden + (size_t)b * L_ * H_;
  float wh = hb[(size_t)(L_ - 1) * H_ + tid];
  Wv[tid] = wh;
  float ch = 0.f;

  {
    const float* kb = hb + (size_t)(NC - 1) * CA * H_;
#pragma unroll
    for (int u = 0; u < 8; ++u) {
      const int off = (u * 8 + wv) * 256;
      load_lds16(kb + off + 4 * lane, &Kc[1][off]);
    }
    const size_t tb = (size_t)b * NC + (NC - 1);
    float2 t2 = *(const float2*)&tmT[tb * (CA * CA) + 2 * tid];
    const int e0 = 2 * tid;
    Tm[(e0 >> 5) * 33 + (e0 & 31)] = t2.x;
    Tm[((e0 + 1) >> 5) * 33 + ((e0 + 1) & 31)] = t2.y;
    if (tid < CA) Dv[tid] = dvec[tb * CA + tid];
  }
  __asm__ volatile("s_waitcnt vmcnt(0)" ::: "memory");
  __syncthreads();
  if (tid < 128) *(float4*)&Kc[1][31 * H_ + 4 * tid] = make_float4(0.f, 0.f, 0.f, 0.f);
  __syncthreads();

  for (int c = NC - 1; c >= 0; --c) {
    const int buf = c & 1;
    float2 tmN = make_float2(0.f, 0.f); float dN = 0.f;
    if (c > 0) {
      const size_t tb = (size_t)b * NC + (c - 1);
      tmN = *(const float2*)&tmT[tb * (CA * CA) + 2 * tid];
      if (tid < CA) dN = dvec[tb * CA + tid];
      const float* kb = hb + (size_t)(c - 1) * CA * H_;
#pragma unroll
      for (int u = 0; u < 8; ++u) {
        const int off = (u * 8 + wv) * 256;
        load_lds16(kb + off + 4 * lane, &Kc[buf ^ 1][off]);
      }
    }
    {
      float4 wa = *(const float4*)&Wv[4 * lane];
      float4 wb = *(const float4*)&Wv[256 + 4 * lane];
#pragma unroll
      for (int i = 0; i < 4; ++i) {
        const int r = 4 * wv + i;
        float4 ka = *(const float4*)&Kc[buf][r * H_ + 4 * lane];
        float4 kc = *(const float4*)&Kc[buf][r * H_ + 256 + 4 * lane];
        float p = ka.x * wa.x;
        p = fmaf(ka.y, wa.y, p); p = fmaf(ka.z, wa.z, p); p = fmaf(ka.w, wa.w, p);
        p = fmaf(kc.x, wb.x, p); p = fmaf(kc.y, wb.y, p);
        p = fmaf(kc.z, wb.z, p); p = fmaf(kc.w, wb.w, p);
        p = wave_reduce_lane63(p);
        if (lane == 63) Yv[r] = p;
      }
    }
    __syncthreads();
    if (wv == 0) {
      const int j = lane & 31, hf = lane >> 5;
      float sig = 0.f;
#pragma unroll
      for (int s0 = 0; s0 < 16; ++s0) {
        const int s = hf * 16 + s0;
        sig = fmaf(Tm[s * 33 + j], Yv[s], sig);
      }
      sig += __shfl_down(sig, 32);
      if (lane < CA) SigS[j] = make_float2(sig, Dv[j] * sig);
    }
    __syncthreads();
    if (c > 0) {
      const int e0 = 2 * tid;
      Tm[(e0 >> 5) * 33 + (e0 & 31)] = tmN.x;
      Tm[((e0 + 1) >> 5) * 33 + ((e0 + 1) & 31)] = tmN.y;
      if (tid < CA) Dv[tid] = dN;
    }
#pragma unroll
    for (int t = 0; t < CA; ++t) {
      float2 ss = SigS[t];
      float kvv = Kc[buf][t * H_ + tid];
      wh = fmaf(-ss.x, kvv, wh);
      ch = fmaf(ss.y, kvv, ch);
    }
    Wv[tid] = wh;
    __asm__ volatile("s_waitcnt vmcnt(0)" ::: "memory");
    __syncthreads();
  }

  Ctx[tid] = ch;
  __syncthreads();
  float acc = bias[tid];
  const float* wr = Wm + (size_t)tid * H_;
#pragma unroll 8
  for (int i = 0; i < H_; i += 4) {
    float4 w4 = *(const float4*)(wr + i);
    float4 cv = *(const float4*)&Ctx[i];
    acc = fmaf(w4.x, cv.x, acc); acc = fmaf(w4.y, cv.y, acc);
    acc = fmaf(w4.z, cv.z, acc); acc = fmaf(w4.w, cv.w, acc);
  }
  out[(size_t)b * H_ + tid] = acc;
}

// =====================================================================
extern "C" void kernel_launch(void* const* d_in, const int* in_sizes, int n_in,
                              void* d_out, int out_size, void* d_ws, size_t ws_size,
                              hipStream_t stream) {
  const float* hidden = (const float*)d_in[0];  // (32, 2048, 512) fp32
  const float* Wm     = (const float*)d_in[1];  // (512, 512) fp32
  const float* bias   = (const float*)d_in[2];  // (512,) fp32
  float* out = (float*)d_out;                   // (32, 512) fp32

  const size_t szKh = (size_t)B_ * L_ * H_ * sizeof(unsigned short);  // 64 MB
  const size_t szTm = (size_t)B_ * NC * CA * CA * sizeof(float);      // 8 MB
  const size_t szD  = (size_t)B_ * NC * CA * sizeof(float);

  dim3 gridA(NC, B_);
  if (ws_size >= szKh + szTm + szD) {
    unsigned short* Kh = (unsigned short*)d_ws;
    float* tmT  = (float*)((char*)d_ws + szKh);
    float* dvec = tmT + (size_t)B_ * NC * CA * CA;
    deltarule_gram<<<gridA, 256, 0, stream>>>(hidden, tmT, dvec, Kh);
    deltarule_scan_f16<<<B_, 512, 0, stream>>>(hidden, Kh, Wm, bias, tmT, dvec, out);
  } else {
    float* tmT  = (float*)d_ws;
    float* dvec = tmT + (size_t)B_ * NC * CA * CA;
    deltarule_gram<<<gridA, 256, 0, stream>>>(hidden, tmT, dvec, nullptr);
    deltarule_scan_f32<<<B_, 512, 0, stream>>>(hidden, Wm, bias, tmT, dvec, out);
  }
}

// Round 6
// 380.889 us; speedup vs baseline: 1.0480x; 1.0480x over previous
//
#include <hip/hip_runtime.h>
#include <hip/hip_fp16.h>

#define B_  32
#define L_  2048
#define H_  512
#define T_  2047      // L_-1 keys enter the scan
#define CA  32        // chunk size
#define NC  64        // chunks per batch (last row padded with zeros)
#define EPSF 1e-6f

// ---- wave64 sum reduction via DPP; full sum lands in lane 63 ----
template <int CTRL>
__device__ __forceinline__ float dpp_shift_add(float x) {
  int t = __builtin_amdgcn_update_dpp(0, __float_as_int(x), CTRL, 0xf, 0xf, true);
  return x + __int_as_float(t);
}
__device__ __forceinline__ float wave_reduce_lane63(float x) {
  x = dpp_shift_add<0x111>(x);  // row_shr:1
  x = dpp_shift_add<0x112>(x);  // row_shr:2
  x = dpp_shift_add<0x114>(x);  // row_shr:4
  x = dpp_shift_add<0x118>(x);  // row_shr:8
  x = dpp_shift_add<0x142>(x);  // row_bcast:15
  x = dpp_shift_add<0x143>(x);  // row_bcast:31
  return x;                     // valid in lane 63
}
__device__ __forceinline__ float rdlane(float v, int l) {
  return __int_as_float(__builtin_amdgcn_readlane(__float_as_int(v), l));
}

// async global->LDS, 16B per lane; LDS base must be wave-uniform
__device__ __forceinline__ void load_lds16(const float* g, float* l) {
  __builtin_amdgcn_global_load_lds(
      (const __attribute__((address_space(1))) unsigned int*)(g),
      (__attribute__((address_space(3))) unsigned int*)(l), 16, 0, 0);
}
__device__ __forceinline__ void load_lds16h(const unsigned short* g, unsigned short* l) {
  __builtin_amdgcn_global_load_lds(
      (const __attribute__((address_space(1))) unsigned int*)(g),
      (__attribute__((address_space(3))) unsigned int*)(l), 16, 0, 0);
}

// =====================================================================
// Kernel A: per (batch, chunk): round keys to fp16, write Kh (row-major
// [t][h]) and KhT (group-interleaved transpose [g][h][e], t = 8g+e), then
// Gram G = K~ K~^T, dvec = diag(G)+eps, X = (I + D^{-1}triu(G,1))^{-1}D^{-1}.
// tmT flat[a*32+b] = X[b][a]  (lane j stores its column j contiguously).
// grid (NC, B_), 256 threads (4 waves).
// =====================================================================
__global__ __launch_bounds__(256) void
deltarule_gram(const float* __restrict__ hidden,
               float* __restrict__ tmT, float* __restrict__ dvec,
               unsigned short* __restrict__ Kh,
               unsigned short* __restrict__ KhT) {
  const int cb = blockIdx.x, b = blockIdx.y;
  const int tid = threadIdx.x, lane = tid & 63, wv = tid >> 6;
  __shared__ __align__(16) float Kc[CA * H_];   // 64 KB
  __shared__ float G[CA * 33];                  // +1 pad

  const float* kb = hidden + ((size_t)b * L_ + (size_t)cb * CA) * H_;
#pragma unroll
  for (int u = 0; u < 16; ++u) {                // 16 issues x 4 waves = 64 segs
    const int off = (u * 4 + wv) * 256;
    load_lds16(kb + off + 4 * lane, &Kc[off]);
  }
  __asm__ volatile("s_waitcnt vmcnt(0)" ::: "memory");
  __syncthreads();
  if (cb == NC - 1) {                           // zero padded key row 31
    if (tid < 128) *(float4*)&Kc[31 * H_ + 4 * tid] = make_float4(0.f, 0.f, 0.f, 0.f);
    __syncthreads();
  }

  // round to fp16 (in place) + write row-major fp16 copy
  if (Kh) {
    unsigned int* dst = (unsigned int*)(Kh + ((size_t)b * L_ + (size_t)cb * CA) * H_);
#pragma unroll
    for (int u = 0; u < 32; ++u) {
      const int i = u * 256 + tid;              // pair index < 8192
      float2 v = *(const float2*)&Kc[2 * i];
      __half2 h2 = __floats2half2_rn(v.x, v.y);
      dst[i] = *(const unsigned int*)&h2;
      *(float2*)&Kc[2 * i] = __half22float2(h2);
    }
    __syncthreads();
  }
  // write transposed group-interleaved copy: KhT[chunk][g][h][e], t=8g+e
  if (KhT) {
    unsigned short* base = KhT + ((size_t)b * NC + cb) * (4 * H_ * 8);
#pragma unroll
    for (int r = 0; r < 2; ++r) {
      const int hh = r * 256 + tid;
#pragma unroll
      for (int g = 0; g < 4; ++g) {
        __half2 h2[4];
#pragma unroll
        for (int e = 0; e < 4; ++e) {
          float a  = Kc[(8 * g + 2 * e) * H_ + hh];
          float b2 = Kc[(8 * g + 2 * e + 1) * H_ + hh];
          h2[e] = __floats2half2_rn(a, b2);
        }
        *(uint4*)(base + (size_t)g * (H_ * 8) + (size_t)hh * 8) = *(const uint4*)h2;
      }
    }
  }

  // register rows: lane covers h in [4*lane,4*lane+4) u [256+4*lane, ...)
  float kr[8][8];
#pragma unroll
  for (int i = 0; i < 8; ++i) {
    const int r = 8 * wv + i;
    *(float4*)&kr[i][0] = *(const float4*)&Kc[r * H_ + 4 * lane];
    *(float4*)&kr[i][4] = *(const float4*)&Kc[r * H_ + 256 + 4 * lane];
  }
  float g[8] = {0.f, 0.f, 0.f, 0.f, 0.f, 0.f, 0.f, 0.f};  // lane j: G[row_i][j]
  for (int j = 8 * wv; j < CA; ++j) {           // only j >= first own row (symmetry)
    float kj[8];
    *(float4*)&kj[0] = *(const float4*)&Kc[j * H_ + 4 * lane];
    *(float4*)&kj[4] = *(const float4*)&Kc[j * H_ + 256 + 4 * lane];
#pragma unroll
    for (int i = 0; i < 8; ++i) {
      float p = kr[i][0] * kj[0];
#pragma unroll
      for (int u = 1; u < 8; ++u) p = fmaf(kr[i][u], kj[u], p);
      p = wave_reduce_lane63(p);
      float s = rdlane(p, 63);
      g[i] = (lane == j) ? s : g[i];
    }
  }
  if (lane < CA) {
#pragma unroll
    for (int i = 0; i < 8; ++i) G[(8 * wv + i) * 33 + lane] = g[i];
  }
  __syncthreads();

  // back-substitution on wave 0: lane j = column j of X
  if (wv == 0) {
    const int j = lane & 31;
    float X[CA];
#pragma unroll
    for (int t = CA - 1; t >= 0; --t) {
      float inner = 0.f;
#pragma unroll
      for (int s = t + 1; s < CA; ++s) inner = fmaf(G[t * 33 + s], X[s], inner);
      X[t] = (((j == t) ? 1.f : 0.f) - inner) / (G[t * 33 + t] + EPSF);
    }
    if (lane < CA) {
      const size_t base = ((size_t)b * NC + cb) * (CA * CA);
#pragma unroll
      for (int u = 0; u < 8; ++u)
        *(float4*)&tmT[base + j * CA + 4 * u] =
            make_float4(X[4 * u], X[4 * u + 1], X[4 * u + 2], X[4 * u + 3]);
      dvec[((size_t)b * NC + cb) * CA + lane] = G[j * 33 + j] + EPSF;
    }
  }
}

// =====================================================================
// Kernel B v3: LDS-minimal backward chunked scan + fused output GEMM.
// grid (B_), 512 threads (8 waves). Wave w owns key rows 4w..4w+3 (dot,
// from global-prefetched VGPRs); thread owns h = tid (update, from LDS
// K^T read as 4x ds_read_b128). sigma/s distributed via v_readlane.
// tmT flat[s*32+j] = X[j][s]: wave w prefetches rows s=4w..4w+3 (global).
// =====================================================================
__global__ __launch_bounds__(512) void
deltarule_scan_v3(const float* __restrict__ hidden,
                  const unsigned short* __restrict__ Kh,
                  const unsigned short* __restrict__ KhT,
                  const float* __restrict__ Wm, const float* __restrict__ bias,
                  const float* __restrict__ tmT, const float* __restrict__ dvec,
                  float* __restrict__ out) {
  const int b = blockIdx.x, tid = threadIdx.x, lane = tid & 63, wv = tid >> 6;
  const int j = lane & 31;
  __shared__ __align__(16) unsigned short KT[3][16384];  // 96 KB (3 x 32 KB)
  __shared__ float Part[8 * 32];                          // sigma partials
  __shared__ __align__(16) float Wsw[H_];                 // swizzled w
  __shared__ __align__(16) float Ctx[H_];

  const unsigned short* khb  = Kh  + (size_t)b * L_ * H_;
  const unsigned short* khtb = KhT + (size_t)b * NC * 16384;

  float wh = hidden[(size_t)b * L_ * H_ + (size_t)(L_ - 1) * H_ + tid];
  // swizzle: h -> word ((h&4)<<6) + ((h>>3)<<2) + (h&3); reads become
  // lane-consecutive float4s at [4*lane] and [256+4*lane].
  const int wswi = ((tid & 4) << 6) + ((tid >> 3) << 2) + (tid & 3);
  Wsw[wswi] = wh;
  float ch = 0.f;

  // ---- preloop: stage KT(63),KT(62); prefetch tmRows/d/rowK for c=63 ----
  {
    const unsigned short* src = khtb + (size_t)(NC - 1) * 16384;
#pragma unroll
    for (int u = 0; u < 4; ++u) {
      const int off = (u * 8 + wv) * 512;
      load_lds16h(src + off + 8 * lane, &KT[(NC - 1) % 3][off]);
    }
  }
  {
    const unsigned short* src = khtb + (size_t)(NC - 2) * 16384;
#pragma unroll
    for (int u = 0; u < 4; ++u) {
      const int off = (u * 8 + wv) * 512;
      load_lds16h(src + off + 8 * lane, &KT[(NC - 2) % 3][off]);
    }
  }
  float tmRow[4], dCur;
  uint4 kr[4];
  {
    const size_t tb = (size_t)b * NC + (NC - 1);
#pragma unroll
    for (int i = 0; i < 4; ++i) tmRow[i] = tmT[tb * 1024 + (4 * wv + i) * 32 + j];
    dCur = dvec[tb * 32 + j];
#pragma unroll
    for (int i = 0; i < 4; ++i)
      kr[i] = *(const uint4*)(khb + ((size_t)(NC - 1) * CA + 4 * wv + i) * H_ + 8 * lane);
  }
  asm volatile("s_waitcnt vmcnt(0) lgkmcnt(0)\n\ts_barrier" ::: "memory");

  for (int c = NC - 1; c >= 0; --c) {
    const int bufc = c % 3;

    // ---- prefetch chunk c-1 regs, then KT(c-2) DMA ----
    float tmN[4], dN = 0.f;
    uint4 kn[4];
    if (c > 0) {
      const size_t tb = (size_t)b * NC + (c - 1);
#pragma unroll
      for (int i = 0; i < 4; ++i) tmN[i] = tmT[tb * 1024 + (4 * wv + i) * 32 + j];
      dN = dvec[tb * 32 + j];
#pragma unroll
      for (int i = 0; i < 4; ++i)
        kn[i] = *(const uint4*)(khb + ((size_t)(c - 1) * CA + 4 * wv + i) * H_ + 8 * lane);
    }
    asm volatile("" ::: "memory");
    if (c >= 2) {
      const unsigned short* src = khtb + (size_t)(c - 2) * 16384;
#pragma unroll
      for (int u = 0; u < 4; ++u) {
        const int off = (u * 8 + wv) * 512;
        load_lds16h(src + off + 8 * lane, &KT[(c - 2) % 3][off]);
      }
    }
    asm volatile("" ::: "memory");

    // ---- dot: y[4wv+i] = K~[row] . w ; y -> SGPRs via readlane(63) ----
    float4 wa  = *(const float4*)&Wsw[4 * lane];
    float4 wb2 = *(const float4*)&Wsw[256 + 4 * lane];
    float ysg[4];
#pragma unroll
    for (int i = 0; i < 4; ++i) {
      float2 f0 = __half22float2(*(__half2*)&kr[i].x);
      float2 f1 = __half22float2(*(__half2*)&kr[i].y);
      float2 f2 = __half22float2(*(__half2*)&kr[i].z);
      float2 f3 = __half22float2(*(__half2*)&kr[i].w);
      float p = f0.x * wa.x;
      p = fmaf(f0.y, wa.y, p); p = fmaf(f1.x, wa.z, p); p = fmaf(f1.y, wa.w, p);
      p = fmaf(f2.x, wb2.x, p); p = fmaf(f2.y, wb2.y, p);
      p = fmaf(f3.x, wb2.z, p); p = fmaf(f3.y, wb2.w, p);
      p = wave_reduce_lane63(p);
      ysg[i] = rdlane(p, 63);
    }

    // ---- sigma partial: sp[j] = sum_i y[4wv+i] * X[j][4wv+i] ----
    float sp = ysg[0] * tmRow[0];
    sp = fmaf(ysg[1], tmRow[1], sp);
    sp = fmaf(ysg[2], tmRow[2], sp);
    sp = fmaf(ysg[3], tmRow[3], sp);
    if (lane < 32) Part[wv * 32 + j] = sp;
    asm volatile("s_waitcnt lgkmcnt(0)\n\ts_barrier" ::: "memory");  // b1

    // ---- combine partials; s = D * sigma ----
    float sig = Part[0 * 32 + j];
#pragma unroll
    for (int w2 = 1; w2 < 8; ++w2) sig += Part[w2 * 32 + j];
    float sv = dCur * sig;

    // ---- update: w -= K^T sigma ; ctx += K^T s  (h = tid; K^T from LDS) ----
    uint4 ktreg[4];
#pragma unroll
    for (int g = 0; g < 4; ++g)
      ktreg[g] = *(const uint4*)&KT[bufc][g * 4096 + tid * 8];
    const __half* kth = (const __half*)ktreg;
#pragma unroll
    for (int t = 0; t < 32; ++t) {
      float sgv = rdlane(sig, t);
      float ssv = rdlane(sv, t);
      float kv = __half2float(kth[t]);
      wh = fmaf(-sgv, kv, wh);
      ch = fmaf(ssv, kv, ch);
    }
    Wsw[wswi] = wh;

    // rotate prefetched regs
    if (c > 0) {
      dCur = dN;
#pragma unroll
      for (int i = 0; i < 4; ++i) { tmRow[i] = tmN[i]; kr[i] = kn[i]; }
    }
    // b_end: vmcnt(4) leaves only KT(c-2) DMA outstanding
    if (c >= 2) {
      asm volatile("s_waitcnt vmcnt(4) lgkmcnt(0)\n\ts_barrier" ::: "memory");
    } else {
      asm volatile("s_waitcnt vmcnt(0) lgkmcnt(0)\n\ts_barrier" ::: "memory");
    }
  }

  // ---- epilogue: out[b] = W @ ctx + bias ----
  Ctx[tid] = ch;
  __syncthreads();
  float acc = bias[tid];
  const float* wr = Wm + (size_t)tid * H_;
#pragma unroll 8
  for (int i = 0; i < H_; i += 4) {
    float4 w4 = *(const float4*)(wr + i);
    float4 cv = *(const float4*)&Ctx[i];
    acc = fmaf(w4.x, cv.x, acc); acc = fmaf(w4.y, cv.y, acc);
    acc = fmaf(w4.z, cv.z, acc); acc = fmaf(w4.w, cv.w, acc);
  }
  out[(size_t)b * H_ + tid] = acc;
}

// =====================================================================
// Kernel B fallback (fp32, round-4 structure) — used if ws too small.
// =====================================================================
__global__ __launch_bounds__(512) void
deltarule_scan_f32(const float* __restrict__ hidden,
                   const float* __restrict__ Wm, const float* __restrict__ bias,
                   const float* __restrict__ tmT, const float* __restrict__ dvec,
                   float* __restrict__ out) {
  const int b = blockIdx.x, tid = threadIdx.x, lane = tid & 63, wv = tid >> 6;
  __shared__ __align__(16) float Kc[2][CA * H_];
  __shared__ float Tm[CA * 33];
  __shared__ float Dv[CA];
  __shared__ float Yv[CA];
  __shared__ float2 SigS[CA];
  __shared__ __align__(16) float Wv[H_];
  __shared__ __align__(16) float Ctx[H_];

  const float* hb = hidden + (size_t)b * L_ * H_;
  float wh = hb[(size_t)(L_ - 1) * H_ + tid];
  Wv[tid] = wh;
  float ch = 0.f;

  {
    const float* kb = hb + (size_t)(NC - 1) * CA * H_;
#pragma unroll
    for (int u = 0; u < 8; ++u) {
      const int off = (u * 8 + wv) * 256;
      load_lds16(kb + off + 4 * lane, &Kc[1][off]);
    }
    const size_t tb = (size_t)b * NC + (NC - 1);
    float2 t2 = *(const float2*)&tmT[tb * (CA * CA) + 2 * tid];
    const int e0 = 2 * tid;
    Tm[(e0 >> 5) * 33 + (e0 & 31)] = t2.x;
    Tm[((e0 + 1) >> 5) * 33 + ((e0 + 1) & 31)] = t2.y;
    if (tid < CA) Dv[tid] = dvec[tb * CA + tid];
  }
  __asm__ volatile("s_waitcnt vmcnt(0)" ::: "memory");
  __syncthreads();
  if (tid < 128) *(float4*)&Kc[1][31 * H_ + 4 * tid] = make_float4(0.f, 0.f, 0.f, 0.f);
  __syncthreads();

  for (int c = NC - 1; c >= 0; --c) {
    const int buf = c & 1;
    float2 tmN = make_float2(0.f, 0.f); float dN = 0.f;
    if (c > 0) {
      const size_t tb = (size_t)b * NC + (c - 1);
      tmN = *(const float2*)&tmT[tb * (CA * CA) + 2 * tid];
      if (tid < CA) dN = dvec[tb * CA + tid];
      const float* kb = hb + (size_t)(c - 1) * CA * H_;
#pragma unroll
      for (int u = 0; u < 8; ++u) {
        const int off = (u * 8 + wv) * 256;
        load_lds16(kb + off + 4 * lane, &Kc[buf ^ 1][off]);
      }
    }
    {
      float4 wa = *(const float4*)&Wv[4 * lane];
      float4 wb = *(const float4*)&Wv[256 + 4 * lane];
#pragma unroll
      for (int i = 0; i < 4; ++i) {
        const int r = 4 * wv + i;
        float4 ka = *(const float4*)&Kc[buf][r * H_ + 4 * lane];
        float4 kc = *(const float4*)&Kc[buf][r * H_ + 256 + 4 * lane];
        float p = ka.x * wa.x;
        p = fmaf(ka.y, wa.y, p); p = fmaf(ka.z, wa.z, p); p = fmaf(ka.w, wa.w, p);
        p = fmaf(kc.x, wb.x, p); p = fmaf(kc.y, wb.y, p);
        p = fmaf(kc.z, wb.z, p); p = fmaf(kc.w, wb.w, p);
        p = wave_reduce_lane63(p);
        if (lane == 63) Yv[r] = p;
      }
    }
    __syncthreads();
    if (wv == 0) {
      const int jj = lane & 31, hf = lane >> 5;
      float sig = 0.f;
#pragma unroll
      for (int s0 = 0; s0 < 16; ++s0) {
        const int s = hf * 16 + s0;
        sig = fmaf(Tm[s * 33 + jj], Yv[s], sig);
      }
      sig += __shfl_down(sig, 32);
      if (lane < CA) SigS[jj] = make_float2(sig, Dv[jj] * sig);
    }
    __syncthreads();
    if (c > 0) {
      const int e0 = 2 * tid;
      Tm[(e0 >> 5) * 33 + (e0 & 31)] = tmN.x;
      Tm[((e0 + 1) >> 5) * 33 + ((e0 + 1) & 31)] = tmN.y;
      if (tid < CA) Dv[tid] = dN;
    }
#pragma unroll
    for (int t = 0; t < CA; ++t) {
      float2 ss = SigS[t];
      float kvv = Kc[buf][t * H_ + tid];
      wh = fmaf(-ss.x, kvv, wh);
      ch = fmaf(ss.y, kvv, ch);
    }
    Wv[tid] = wh;
    __asm__ volatile("s_waitcnt vmcnt(0)" ::: "memory");
    __syncthreads();
  }

  Ctx[tid] = ch;
  __syncthreads();
  float acc = bias[tid];
  const float* wr = Wm + (size_t)tid * H_;
#pragma unroll 8
  for (int i = 0; i < H_; i += 4) {
    float4 w4 = *(const float4*)(wr + i);
    float4 cv = *(const float4*)&Ctx[i];
    acc = fmaf(w4.x, cv.x, acc); acc = fmaf(w4.y, cv.y, acc);
    acc = fmaf(w4.z, cv.z, acc); acc = fmaf(w4.w, cv.w, acc);
  }
  out[(size_t)b * H_ + tid] = acc;
}

// =====================================================================
extern "C" void kernel_launch(void* const* d_in, const int* in_sizes, int n_in,
                              void* d_out, int out_size, void* d_ws, size_t ws_size,
                              hipStream_t stream) {
  const float* hidden = (const float*)d_in[0];  // (32, 2048, 512) fp32
  const float* Wm     = (const float*)d_in[1];  // (512, 512) fp32
  const float* bias   = (const float*)d_in[2];  // (512,) fp32
  float* out = (float*)d_out;                   // (32, 512) fp32

  const size_t szKh  = (size_t)B_ * L_ * H_ * sizeof(unsigned short);   // 64 MB
  const size_t szKhT = (size_t)B_ * NC * 16384 * sizeof(unsigned short);// 64 MB
  const size_t szTm  = (size_t)B_ * NC * CA * CA * sizeof(float);       // 8 MB
  const size_t szD   = (size_t)B_ * NC * CA * sizeof(float);

  dim3 gridA(NC, B_);
  if (ws_size >= szKh + szKhT + szTm + szD) {
    unsigned short* Kh  = (unsigned short*)d_ws;
    unsigned short* KhT = (unsigned short*)((char*)d_ws + szKh);
    float* tmT  = (float*)((char*)d_ws + szKh + szKhT);
    float* dvec = tmT + (size_t)B_ * NC * CA * CA;
    deltarule_gram<<<gridA, 256, 0, stream>>>(hidden, tmT, dvec, Kh, KhT);
    deltarule_scan_v3<<<B_, 512, 0, stream>>>(hidden, Kh, KhT, Wm, bias, tmT, dvec, out);
  } else {
    float* tmT  = (float*)d_ws;
    float* dvec = tmT + (size_t)B_ * NC * CA * CA;
    deltarule_gram<<<gridA, 256, 0, stream>>>(hidden, tmT, dvec, nullptr, nullptr);
    deltarule_scan_f32<<<B_, 512, 0, stream>>>(hidden, Wm, bias, tmT, dvec, out);
  }
}